// Round 5
// baseline (162.488 us; speedup 1.0000x reference)
//
#include <hip/hip_runtime.h>
#include <math.h>

#define KMAX   32
#define CIN    64
#define COUT   64
#define NKERN  27
#define PPW    8          // points per wave
constexpr float BN_EPS = 1e-5f;

typedef _Float16 f16;
typedef _Float16 f16x2 __attribute__((ext_vector_type(2)));
typedef _Float16 f16x8 __attribute__((ext_vector_type(8)));

#if __has_builtin(__builtin_amdgcn_fdot2)
#define FDOT2(a, b, c) __builtin_amdgcn_fdot2((a), (b), (c), false)
#else
static __device__ inline float FDOT2(f16x2 a, f16x2 b, float c) {
    return fmaf((float)a.x, (float)b.x, fmaf((float)a.y, (float)b.y, c));
}
#endif

// ---------------- kernel 0: zero the stats accumulator ----------------
__global__ void k_zero(float* stats) {
    stats[threadIdx.x] = 0.0f;   // 128 threads: [0..63]=sum, [64..127]=sumsq
}

// ---------------- kernel A: convert inputs f32 -> f16 -----------------
__global__ __launch_bounds__(256) void k_cvt(const float* __restrict__ in,
                                             f16* __restrict__ out, int total4) {
    const int stride = gridDim.x * blockDim.x;
    for (int i = blockIdx.x * blockDim.x + threadIdx.x; i < total4; i += stride) {
        const float4 v = ((const float4*)in)[i];
        f16x2 a = { (f16)v.x, (f16)v.y };
        f16x2 b = { (f16)v.z, (f16)v.w };
        uint2 u;
        u.x = *(const unsigned int*)&a;
        u.y = *(const unsigned int*)&b;
        ((uint2*)out)[i] = u;
    }
}

// ---------------- kernel 1: gather-conv + 64x64 matmul + relu --------
// Pair-row gather: lanes 0-31 = even neighbor of pair, lanes 32-63 = odd.
// Each lane loads f16x2 (channels 2c,2c+1). All 32 neighbors gathered
// unconditionally; validity masked at FMA. dw held in regs (32 f16x2/lane);
// sp broadcast via ds_read_b128. Next point's indices prefetched.
__global__ __launch_bounds__(256, 3) void k_conv(
    const f16*   __restrict__ gh,          // f16[N,64]
    const float* __restrict__ sw,          // [27, 64, 1]
    const float* __restrict__ dw,          // [64, 64]
    const float* __restrict__ bias,        // [1, 64]
    const int*   __restrict__ nn_count,    // [N]
    const int*   __restrict__ nn_index,    // [N, 32]
    const int*   __restrict__ filt_index,  // [N, 32]
    float*       __restrict__ xout,        // [N, 64]  pre-BN (relu'd)
    float*       __restrict__ stats)       // [128]
{
    __shared__ f16   sw_lds[NKERN * CIN];      // 3.4 KB, f16
    __shared__ f16x2 sp_lds[4][CIN / 2];       // 0.5 KB per-wave sp broadcast
    __shared__ float red[2][4][COUT];          // 2 KB stats reduction

    const int tid = threadIdx.x;
    for (int i = tid; i < NKERN * CIN; i += 256) sw_lds[i] = (f16)sw[i];
    __syncthreads();

    const int wave = tid >> 6;
    const int lane = tid & 63;
    const int half = lane >> 5;     // which neighbor of the pair
    const int cpos = lane & 31;     // channel pair: ch = 2*cpos, 2*cpos+1

    // lane j holds dw column j as 32 packed f16x2 (register-resident)
    f16x2 dwr[CIN / 2];
    #pragma unroll
    for (int c2 = 0; c2 < CIN / 2; ++c2) {
        f16x2 w = { (f16)dw[(2 * c2) * COUT + lane],
                    (f16)dw[(2 * c2 + 1) * COUT + lane] };
        dwr[c2] = w;
    }
    const float b = bias[lane];

    const int base = blockIdx.x * (4 * PPW) + wave * PPW;
    float sum = 0.0f, sumsq = 0.0f;

    int cnts[PPW];
    #pragma unroll
    for (int p = 0; p < PPW; ++p) cnts[p] = nn_count[base + p];

    int4 idxA[8];
    {
        const int4* ni4 = (const int4*)(nn_index + (size_t)base * KMAX);
        #pragma unroll
        for (int q = 0; q < 8; ++q) idxA[q] = ni4[q];
    }

    #pragma unroll
    for (int p = 0; p < PPW; ++p) {
        const int n   = base + p;
        const int cnt = cnts[p];

        // ---- issue 16 pair-gathers (32 rows) from prefetched idxA ----
        f16x2 g[16];
        #pragma unroll
        for (int i = 0; i < 8; ++i) {
            const int4 q = idxA[i];                 // neighbors 4i..4i+3
            const int rowA = half ? q.y : q.x;      // pair (4i, 4i+1)
            const int rowB = half ? q.w : q.z;      // pair (4i+2, 4i+3)
            g[2 * i]     = *(const f16x2*)(gh + (size_t)rowA * CIN + 2 * cpos);
            g[2 * i + 1] = *(const f16x2*)(gh + (size_t)rowB * CIN + 2 * cpos);
        }

        // ---- filter indices for this point (latency hides under gathers)
        int4 fltA[8];
        {
            const int4* fi4 = (const int4*)(filt_index + (size_t)n * KMAX);
            #pragma unroll
            for (int q = 0; q < 8; ++q) fltA[q] = fi4[q];
        }

        // ---- prefetch next point's neighbor indices ----
        int4 idxB[8];
        if (p + 1 < PPW) {
            const int4* ni4 = (const int4*)(nn_index + (size_t)(n + 1) * KMAX);
            #pragma unroll
            for (int q = 0; q < 8; ++q) idxB[q] = ni4[q];
        }

        // ---- masked FMA over 32 neighbors (2 channels/lane) ----
        float a0x = 0.f, a0y = 0.f, a1x = 0.f, a1y = 0.f;
        const f16x2 zero2 = { (f16)0.f, (f16)0.f };
        #pragma unroll
        for (int i = 0; i < 8; ++i) {
            const int4 qf = fltA[i];
            {
                const int  fl = half ? qf.y : qf.x;
                const f16x2 w = *(const f16x2*)&sw_lds[fl * CIN + 2 * cpos];
                const f16x2 gv = ((4 * i + half) < cnt) ? g[2 * i] : zero2;
                a0x = fmaf((float)gv.x, (float)w.x, a0x);
                a0y = fmaf((float)gv.y, (float)w.y, a0y);
            }
            {
                const int  fl = half ? qf.w : qf.z;
                const f16x2 w = *(const f16x2*)&sw_lds[fl * CIN + 2 * cpos];
                const f16x2 gv = ((4 * i + 2 + half) < cnt) ? g[2 * i + 1] : zero2;
                a1x = fmaf((float)gv.x, (float)w.x, a1x);
                a1y = fmaf((float)gv.y, (float)w.y, a1y);
            }
        }
        float ax = a0x + a1x;
        float ay = a0y + a1y;

        // ---- cross-half reduce (even-k partial + odd-k partial) ----
        ax += __shfl_xor(ax, 32);
        ay += __shfl_xor(ay, 32);
        const float inv = 1.0f / (float)cnt;
        f16x2 sp2 = { (f16)(ax * inv), (f16)(ay * inv) };
        sp_lds[wave][cpos] = sp2;   // both halves write same value (benign)

        // ---- 64x64 matmul: sp broadcast as f16x8, dw in regs ----
        const f16x8* sp8 = (const f16x8*)&sp_lds[wave][0];
        float x0 = b, x1 = 0.f, x2 = 0.f, x3 = 0.f;
        #pragma unroll
        for (int c8 = 0; c8 < 8; ++c8) {
            const f16x8 v = sp8[c8];
            x0 = FDOT2(__builtin_shufflevector(v, v, 0, 1), dwr[4 * c8 + 0], x0);
            x1 = FDOT2(__builtin_shufflevector(v, v, 2, 3), dwr[4 * c8 + 1], x1);
            x2 = FDOT2(__builtin_shufflevector(v, v, 4, 5), dwr[4 * c8 + 2], x2);
            x3 = FDOT2(__builtin_shufflevector(v, v, 6, 7), dwr[4 * c8 + 3], x3);
        }
        float xv = fmaxf((x0 + x1) + (x2 + x3), 0.0f);

        xout[(size_t)n * COUT + lane] = xv;
        sum   += xv;
        sumsq += xv * xv;

        #pragma unroll
        for (int q = 0; q < 8; ++q) idxA[q] = idxB[q];
    }

    red[0][wave][lane] = sum;
    red[1][wave][lane] = sumsq;
    __syncthreads();
    if (wave == 0) {
        float s = red[0][0][lane] + red[0][1][lane] + red[0][2][lane] + red[0][3][lane];
        float q = red[1][0][lane] + red[1][1][lane] + red[1][2][lane] + red[1][3][lane];
        atomicAdd(&stats[lane], s);
        atomicAdd(&stats[COUT + lane], q);
    }
}

// ---------------- kernel 2: finalize BN scale/shift -------------------
__global__ void k_finalize(const float* __restrict__ stats,
                           const float* __restrict__ gamma,
                           const float* __restrict__ beta,
                           float* __restrict__ sc_sh, float invN) {
    const int j = threadIdx.x;               // 64 threads
    const float mean = stats[j] * invN;
    const float var  = stats[COUT + j] * invN - mean * mean;
    const float s    = gamma[j] * rsqrtf(var + BN_EPS);
    sc_sh[j]        = s;
    sc_sh[COUT + j] = beta[j] - mean * s;
}

// ---------------- kernel 3: apply BN in place on d_out ----------------
__global__ __launch_bounds__(256) void k_apply(float* __restrict__ x,
                                               const float* __restrict__ sc_sh,
                                               int total4) {
    __shared__ float s[COUT], sh[COUT];
    if (threadIdx.x < COUT) {
        s[threadIdx.x]  = sc_sh[threadIdx.x];
        sh[threadIdx.x] = sc_sh[COUT + threadIdx.x];
    }
    __syncthreads();
    const int stride = gridDim.x * blockDim.x;
    for (int idx = blockIdx.x * blockDim.x + threadIdx.x; idx < total4; idx += stride) {
        float4 v = ((const float4*)x)[idx];
        const int j = (idx * 4) & (COUT - 1);
        v.x = fmaf(v.x, s[j],     sh[j]);
        v.y = fmaf(v.y, s[j + 1], sh[j + 1]);
        v.z = fmaf(v.z, s[j + 2], sh[j + 2]);
        v.w = fmaf(v.w, s[j + 3], sh[j + 3]);
        ((float4*)x)[idx] = v;
    }
}

extern "C" void kernel_launch(void* const* d_in, const int* in_sizes, int n_in,
                              void* d_out, int out_size, void* d_ws, size_t ws_size,
                              hipStream_t stream) {
    const float* inputs     = (const float*)d_in[0];
    const float* sw         = (const float*)d_in[1];
    const float* dw         = (const float*)d_in[2];
    const float* bias       = (const float*)d_in[3];
    const float* gamma      = (const float*)d_in[4];
    const float* beta       = (const float*)d_in[5];
    const int*   nn_count   = (const int*)d_in[6];
    const int*   nn_index   = (const int*)d_in[7];
    const int*   filt_index = (const int*)d_in[8];

    const int N = in_sizes[0] / CIN;           // 65536
    float* x     = (float*)d_out;              // pre-BN activations, then final out
    float* stats = (float*)d_ws;               // [0..127]
    float* sc_sh = (float*)d_ws + 128;         // [128..255]
    f16*   in_h  = (f16*)((float*)d_ws + 256); // N*64 halves

    k_zero<<<1, 128, 0, stream>>>(stats);
    k_cvt<<<2048, 256, 0, stream>>>(inputs, in_h, N * CIN / 4);

    const int blocks = N / (4 * PPW);          // 2048
    k_conv<<<blocks, 256, 0, stream>>>(
        in_h, sw, dw, bias, nn_count, nn_index, filt_index, x, stats);

    k_finalize<<<1, COUT, 0, stream>>>(stats, gamma, beta, sc_sh, 1.0f / (float)N);

    const int total4 = N * COUT / 4;
    k_apply<<<2048, 256, 0, stream>>>(x, sc_sh, total4);
}